// Round 1
// baseline (2527.111 us; speedup 1.0000x reference)
//
#include <hip/hip_runtime.h>

#define HID 64
#define IN_C 16

// h = relu(x @ W0 + b0); one thread per (node, out-channel)
__global__ void k_node0(const float* __restrict__ x, const float* __restrict__ W0,
                        const float* __restrict__ b0, float* __restrict__ h, int N) {
    int gid = blockIdx.x * blockDim.x + threadIdx.x;
    int total = N * HID;
    if (gid >= total) return;
    int n = gid >> 6;
    int c = gid & 63;
    const float* xr = x + (size_t)n * IN_C;
    float acc = b0[c];
#pragma unroll
    for (int k = 0; k < IN_C; ++k) acc = fmaf(xr[k], W0[k * HID + c], acc);
    h[gid] = fmaxf(acc, 0.f);
}

__global__ void k_zero(float* __restrict__ p, int n4) {
    int gid = blockIdx.x * blockDim.x + threadIdx.x;
    int stride = gridDim.x * blockDim.x;
    float4 z = {0.f, 0.f, 0.f, 0.f};
    for (int i = gid; i < n4; i += stride) reinterpret_cast<float4*>(p)[i] = z;
}

// Per edge: s[dst][:] += h[src][:]; deg[dst] += 1.  Wave per edge, lane = channel.
__global__ void k_edge(const int* __restrict__ ei, const float* __restrict__ h,
                       float* __restrict__ s, float* __restrict__ deg, int E) {
    int tid = blockIdx.x * blockDim.x + threadIdx.x;
    int lane = threadIdx.x & 63;
    int wid = tid >> 6;
    int nw = (gridDim.x * blockDim.x) >> 6;
    for (int e = wid; e < E; e += nw) {
        int srcn = ei[e];
        int dstn = ei[E + e];
        float v = h[(size_t)srcn * HID + lane];
        atomicAdd(&s[(size_t)dstn * HID + lane], v);
        if (lane == 0) atomicAdd(&deg[dstn], 1.f);
    }
}

// Fused: mp = (s@Mt)/deg + h@Mb + bM0 (if deg>0); h2 = h+mp; h3 = relu(h2@W1+b1);
// out = h3@W2 + b2.  Wave per node; Mt/Mb/W1 columns register-resident per lane.
__global__ __launch_bounds__(256, 2) void k_final(
    const float* __restrict__ h, const float* __restrict__ s, const float* __restrict__ deg,
    const float* __restrict__ M0, const float* __restrict__ bM0,
    const float* __restrict__ W1, const float* __restrict__ b1,
    const float* __restrict__ W2, const float* __restrict__ b2,
    float* __restrict__ out, int N)
{
    int lane = threadIdx.x & 63;
    int wid = (blockIdx.x * blockDim.x + threadIdx.x) >> 6;
    int nw = (gridDim.x * blockDim.x) >> 6;

    // register-resident weight columns: lane c holds column c
    float mt[HID], mb[HID], w1c[HID];
#pragma unroll
    for (int k = 0; k < HID; ++k) {
        mt[k]  = M0[k * HID + lane];            // Mt[k][lane]
        mb[k]  = M0[(HID + k) * HID + lane];    // Mb[k][lane]
        w1c[k] = W1[k * HID + lane];
    }
    float bM0l = bM0[lane];
    float b1l  = b1[lane];
    float w2l  = W2[lane];
    float b2s  = b2[0];

    for (int n = wid; n < N; n += nw) {
        float sv = s[(size_t)n * HID + lane];
        float hv = h[(size_t)n * HID + lane];
        float dg = deg[n];

        float t1 = 0.f, t2 = 0.f;
#pragma unroll
        for (int k = 0; k < HID; ++k) {
            float sk = __shfl(sv, k);
            float hk = __shfl(hv, k);
            t1 = fmaf(sk, mt[k], t1);
            t2 = fmaf(hk, mb[k], t2);
        }
        float mp = (dg > 0.f) ? (t1 / dg + t2 + bM0l) : 0.f;
        float h2 = hv + mp;

        float acc = b1l;
#pragma unroll
        for (int k = 0; k < HID; ++k) {
            float hk = __shfl(h2, k);
            acc = fmaf(hk, w1c[k], acc);
        }
        float h3 = fmaxf(acc, 0.f);

        float p = h3 * w2l;
#pragma unroll
        for (int off = 32; off > 0; off >>= 1) p += __shfl_down(p, off);
        if (lane == 0) out[n] = p + b2s;
    }
}

extern "C" void kernel_launch(void* const* d_in, const int* in_sizes, int n_in,
                              void* d_out, int out_size, void* d_ws, size_t ws_size,
                              hipStream_t stream) {
    const float* x   = (const float*)d_in[0];
    const int*   ei  = (const int*)d_in[1];
    const float* W0  = (const float*)d_in[2];
    const float* b0  = (const float*)d_in[3];
    const float* W1  = (const float*)d_in[4];
    const float* b1  = (const float*)d_in[5];
    const float* W2  = (const float*)d_in[6];
    const float* b2  = (const float*)d_in[7];
    const float* M0  = (const float*)d_in[8];
    const float* bM0 = (const float*)d_in[9];

    int N = in_sizes[0] / IN_C;
    int E = in_sizes[1] / 2;

    float* h   = (float*)d_ws;
    float* s   = h + (size_t)N * HID;
    float* deg = s + (size_t)N * HID;   // contiguous after s
    float* out = (float*)d_out;

    // 1) h = relu(x@W0+b0)
    k_node0<<<(N * HID + 255) / 256, 256, 0, stream>>>(x, W0, b0, h, N);
    // 2) zero s and deg (contiguous, N*64 + N floats, multiple of 4)
    k_zero<<<2048, 256, 0, stream>>>(s, (N * HID + N) / 4);
    // 3) edge scatter-add
    k_edge<<<2048, 256, 0, stream>>>(ei, h, s, deg, E);
    // 4) fused message combine + layer1 + layer2
    k_final<<<512, 256, 0, stream>>>(h, s, deg, M0, bM0, W1, b1, W2, b2, out, N);
}

// Round 2
// 634.178 us; speedup vs baseline: 3.9849x; 3.9849x over previous
//
#include <hip/hip_runtime.h>

#define HID 64
#define IN_C 16
#define R 4

__device__ __forceinline__ float lanebc(float v, int l) {
    return __int_as_float(__builtin_amdgcn_readlane(__float_as_int(v), l));
}

// h = relu(x @ W0 + b0); one thread per (node, out-channel)
__global__ void k_node0(const float* __restrict__ x, const float* __restrict__ W0,
                        const float* __restrict__ b0, float* __restrict__ h, int N) {
    int gid = blockIdx.x * blockDim.x + threadIdx.x;
    int total = N * HID;
    if (gid >= total) return;
    int n = gid >> 6;
    int c = gid & 63;
    const float* xr = x + (size_t)n * IN_C;
    float acc = b0[c];
#pragma unroll
    for (int k = 0; k < IN_C; ++k) acc = fmaf(xr[k], W0[k * HID + c], acc);
    h[gid] = fmaxf(acc, 0.f);
}

__global__ void k_zero(float* __restrict__ p, int n4) {
    int gid = blockIdx.x * blockDim.x + threadIdx.x;
    int stride = gridDim.x * blockDim.x;
    float4 z = {0.f, 0.f, 0.f, 0.f};
    for (int i = gid; i < n4; i += stride) reinterpret_cast<float4*>(p)[i] = z;
}

// Per edge: s[dst][:] += h[src][:]; deg[dst] += 1.  Wave per edge, lane = channel.
__global__ void k_edge(const int* __restrict__ ei, const float* __restrict__ h,
                       float* __restrict__ s, float* __restrict__ deg, int E) {
    int tid = blockIdx.x * blockDim.x + threadIdx.x;
    int lane = threadIdx.x & 63;
    int wid = tid >> 6;
    int nw = (gridDim.x * blockDim.x) >> 6;
    for (int e = wid; e < E; e += nw) {
        int srcn = ei[e];
        int dstn = ei[E + e];
        float v = h[(size_t)srcn * HID + lane];
        atomicAdd(&s[(size_t)dstn * HID + lane], v);
        if (lane == 0) atomicAdd(&deg[dstn], 1.f);
    }
}

// Fused: mp = (s@Mt)/deg + h@Mb + bM0 (if deg>0); h2 = h+mp; h3 = relu(h2@W1+b1);
// out = h3@W2 + b2.  Weights in LDS (48KB/block); R=4 nodes per wave per pass;
// cross-lane broadcast via v_readlane (no per-lane weight arrays -> no spill).
__global__ __launch_bounds__(256) void k_final(
    const float* __restrict__ h, const float* __restrict__ s, const float* __restrict__ deg,
    const float* __restrict__ M0, const float* __restrict__ bM0,
    const float* __restrict__ W1, const float* __restrict__ b1,
    const float* __restrict__ W2, const float* __restrict__ b2,
    float* __restrict__ out, int N)
{
    __shared__ float ldsMt[HID * HID];
    __shared__ float ldsMb[HID * HID];
    __shared__ float ldsW1[HID * HID];

    for (int i = threadIdx.x; i < HID * HID; i += 256) {
        ldsMt[i] = M0[i];                 // Mt[k][c] = M0[k*64+c], k<64
        ldsMb[i] = M0[HID * HID + i];     // Mb[k][c] = M0[(64+k)*64+c]
        ldsW1[i] = W1[i];
    }
    __syncthreads();

    int lane = threadIdx.x & 63;
    int wid = (blockIdx.x * blockDim.x + threadIdx.x) >> 6;
    int nw = (gridDim.x * blockDim.x) >> 6;

    float bM0l = bM0[lane];
    float b1l  = b1[lane];
    float w2l  = W2[lane];
    float b2s  = b2[0];

    for (int n0 = wid * R; n0 < N; n0 += nw * R) {
        float sv[R], hv[R], t1[R], t2[R];
#pragma unroll
        for (int r = 0; r < R; ++r) {
            int n = n0 + r;
            bool ok = n < N;
            sv[r] = ok ? s[(size_t)n * HID + lane] : 0.f;
            hv[r] = ok ? h[(size_t)n * HID + lane] : 0.f;
            t1[r] = 0.f;
            t2[r] = 0.f;
        }
#pragma unroll
        for (int k = 0; k < HID; ++k) {
            float wmt = ldsMt[k * HID + lane];
            float wmb = ldsMb[k * HID + lane];
#pragma unroll
            for (int r = 0; r < R; ++r) {
                t1[r] = fmaf(lanebc(sv[r], k), wmt, t1[r]);
                t2[r] = fmaf(lanebc(hv[r], k), wmb, t2[r]);
            }
        }
        float h2[R], acc[R];
#pragma unroll
        for (int r = 0; r < R; ++r) {
            int n = n0 + r;
            float dg = (n < N) ? deg[n] : 0.f;
            float mp = (dg > 0.f) ? (t1[r] / dg + t2[r] + bM0l) : 0.f;
            h2[r] = hv[r] + mp;
            acc[r] = b1l;
        }
#pragma unroll
        for (int k = 0; k < HID; ++k) {
            float w1 = ldsW1[k * HID + lane];
#pragma unroll
            for (int r = 0; r < R; ++r)
                acc[r] = fmaf(lanebc(h2[r], k), w1, acc[r]);
        }
#pragma unroll
        for (int r = 0; r < R; ++r) {
            float p = fmaxf(acc[r], 0.f) * w2l;
#pragma unroll
            for (int off = 32; off > 0; off >>= 1) p += __shfl_down(p, off);
            if (lane == 0 && (n0 + r) < N) out[n0 + r] = p + b2s;
        }
    }
}

extern "C" void kernel_launch(void* const* d_in, const int* in_sizes, int n_in,
                              void* d_out, int out_size, void* d_ws, size_t ws_size,
                              hipStream_t stream) {
    const float* x   = (const float*)d_in[0];
    const int*   ei  = (const int*)d_in[1];
    const float* W0  = (const float*)d_in[2];
    const float* b0  = (const float*)d_in[3];
    const float* W1  = (const float*)d_in[4];
    const float* b1  = (const float*)d_in[5];
    const float* W2  = (const float*)d_in[6];
    const float* b2  = (const float*)d_in[7];
    const float* M0  = (const float*)d_in[8];
    const float* bM0 = (const float*)d_in[9];

    int N = in_sizes[0] / IN_C;
    int E = in_sizes[1] / 2;

    float* h   = (float*)d_ws;
    float* s   = h + (size_t)N * HID;
    float* deg = s + (size_t)N * HID;   // contiguous after s
    float* out = (float*)d_out;

    // 1) h = relu(x@W0+b0)
    k_node0<<<(N * HID + 255) / 256, 256, 0, stream>>>(x, W0, b0, h, N);
    // 2) zero s and deg (contiguous, N*65 floats, multiple of 4)
    k_zero<<<2048, 256, 0, stream>>>(s, (N * HID + N) / 4);
    // 3) edge scatter-add
    k_edge<<<2048, 256, 0, stream>>>(ei, h, s, deg, E);
    // 4) fused message combine + layer1 + layer2
    k_final<<<768, 256, 0, stream>>>(h, s, deg, M0, bM0, W1, b1, W2, b2, out, N);
}

// Round 3
// 547.306 us; speedup vs baseline: 4.6174x; 1.1587x over previous
//
#include <hip/hip_runtime.h>

#define HID 64
#define IN_C 16
#define R 4

__device__ __forceinline__ float lanebc(float v, int l) {
    return __int_as_float(__builtin_amdgcn_readlane(__float_as_int(v), l));
}

// h = relu(x @ W0 + b0); one thread per (node, out-channel)
__global__ void k_node0(const float* __restrict__ x, const float* __restrict__ W0,
                        const float* __restrict__ b0, float* __restrict__ h, int N) {
    int gid = blockIdx.x * blockDim.x + threadIdx.x;
    int total = N * HID;
    if (gid >= total) return;
    int n = gid >> 6;
    int c = gid & 63;
    const float* xr = x + (size_t)n * IN_C;
    float acc = b0[c];
#pragma unroll
    for (int k = 0; k < IN_C; ++k) acc = fmaf(xr[k], W0[k * HID + c], acc);
    h[gid] = fmaxf(acc, 0.f);
}

__global__ void k_zero_int(int* __restrict__ p, int n) {
    int gid = blockIdx.x * blockDim.x + threadIdx.x;
    int stride = gridDim.x * blockDim.x;
    for (int i = gid; i < n; i += stride) p[i] = 0;
}

// cnt[dst]++ per edge (int atomics on 400KB array)
__global__ void k_hist(const int* __restrict__ ei, int* __restrict__ cnt, int E) {
    int e = blockIdx.x * blockDim.x + threadIdx.x;
    if (e < E) atomicAdd(&cnt[ei[E + e]], 1);
}

// Per-block (1024 elems) exclusive scan of cnt -> row_start; block sums -> bsum
__global__ void k_scan1(const int* __restrict__ cnt, int* __restrict__ rs,
                        int* __restrict__ bsum, int N) {
    __shared__ int lds[256];
    int t = threadIdx.x;
    int base = blockIdx.x * 1024 + t * 4;
    int v0 = 0, v1 = 0, v2 = 0, v3 = 0;
    if (base + 3 < N) {
        int4 v = *reinterpret_cast<const int4*>(cnt + base);
        v0 = v.x; v1 = v.y; v2 = v.z; v3 = v.w;
    } else {
        if (base + 0 < N) v0 = cnt[base + 0];
        if (base + 1 < N) v1 = cnt[base + 1];
        if (base + 2 < N) v2 = cnt[base + 2];
        if (base + 3 < N) v3 = cnt[base + 3];
    }
    int s = v0 + v1 + v2 + v3;
    lds[t] = s;
    __syncthreads();
#pragma unroll
    for (int off = 1; off < 256; off <<= 1) {
        int x = (t >= off) ? lds[t - off] : 0;
        __syncthreads();
        lds[t] += x;
        __syncthreads();
    }
    int excl = lds[t] - s;
    if (t == 255) bsum[blockIdx.x] = lds[255];
    if (base + 0 < N) rs[base + 0] = excl;
    if (base + 1 < N) rs[base + 1] = excl + v0;
    if (base + 2 < N) rs[base + 2] = excl + v0 + v1;
    if (base + 3 < N) rs[base + 3] = excl + v0 + v1 + v2;
}

// single-block exclusive scan of bsum (NB <= 256)
__global__ void k_scan_top(int* __restrict__ bsum, int NB) {
    __shared__ int lds[256];
    int t = threadIdx.x;
    int v = (t < NB) ? bsum[t] : 0;
    lds[t] = v;
    __syncthreads();
#pragma unroll
    for (int off = 1; off < 256; off <<= 1) {
        int x = (t >= off) ? lds[t - off] : 0;
        __syncthreads();
        lds[t] += x;
        __syncthreads();
    }
    if (t < NB) bsum[t] = lds[t] - v;
}

// rs[i] += bsum[i>>10]; cursor[i] = rs[i]; rs[N] = E
__global__ void k_scan_add(int* __restrict__ rs, int* __restrict__ cursor,
                           const int* __restrict__ bsum, int N, int E) {
    int i = blockIdx.x * blockDim.x + threadIdx.x;
    if (i < N) {
        int v = rs[i] + bsum[i >> 10];
        rs[i] = v;
        cursor[i] = v;
    }
    if (i == 0) rs[N] = E;
}

// csr_src[atomicAdd(cursor[dst])] = src
__global__ void k_scatter(const int* __restrict__ ei, int* __restrict__ cursor,
                          int* __restrict__ csr, int E) {
    int e = blockIdx.x * blockDim.x + threadIdx.x;
    if (e >= E) return;
    int srcn = ei[e];
    int dstn = ei[E + e];
    int pos = atomicAdd(&cursor[dstn], 1);
    csr[pos] = srcn;
}

// Fused: gather-aggregate sv = sum h[src]; mp = (sv@Mt)/deg + h@Mb + bM0 (deg>0);
// h2 = h+mp; h3 = relu(h2@W1+b1); out = h3@W2 + b2.
// Wave per R=4 nodes; weights in LDS; broadcast via v_readlane.
__global__ __launch_bounds__(512) void k_final(
    const float* __restrict__ h, const int* __restrict__ rs, const int* __restrict__ csr,
    const float* __restrict__ M0, const float* __restrict__ bM0,
    const float* __restrict__ W1, const float* __restrict__ b1,
    const float* __restrict__ W2, const float* __restrict__ b2,
    float* __restrict__ out, int N)
{
    __shared__ float ldsMt[HID * HID];
    __shared__ float ldsMb[HID * HID];
    __shared__ float ldsW1[HID * HID];

    for (int i = threadIdx.x; i < HID * HID; i += 512) {
        ldsMt[i] = M0[i];                 // Mt[k][c] = M0[k*64+c]
        ldsMb[i] = M0[HID * HID + i];     // Mb[k][c]
        ldsW1[i] = W1[i];
    }
    __syncthreads();

    int lane = threadIdx.x & 63;
    int wid = (blockIdx.x * blockDim.x + threadIdx.x) >> 6;
    int nw = (gridDim.x * blockDim.x) >> 6;

    float bM0l = bM0[lane];
    float b1l  = b1[lane];
    float w2l  = W2[lane];
    float b2s  = b2[0];

    const float* hl = h + lane;

    for (int n0 = wid * R; n0 < N; n0 += nw * R) {
        float sv[R], hv[R], dg[R];
#pragma unroll
        for (int r = 0; r < R; ++r) {
            int n = n0 + r;
            bool ok = n < N;
            hv[r] = ok ? h[(size_t)n * HID + lane] : 0.f;
            int beg = ok ? rs[n] : 0;
            int end = ok ? rs[n + 1] : 0;
            dg[r] = (float)(end - beg);
            float acc = 0.f;
            int i = beg;
            for (; i + 4 <= end; i += 4) {   // 4 independent loads in flight
                int i0 = csr[i], i1 = csr[i + 1], i2 = csr[i + 2], i3 = csr[i + 3];
                float a = hl[(size_t)i0 * HID];
                float b = hl[(size_t)i1 * HID];
                float c = hl[(size_t)i2 * HID];
                float d = hl[(size_t)i3 * HID];
                acc += a; acc += b; acc += c; acc += d;
            }
            for (; i < end; ++i) acc += hl[(size_t)csr[i] * HID];
            sv[r] = acc;
        }

        float t1[R], t2[R];
#pragma unroll
        for (int r = 0; r < R; ++r) { t1[r] = 0.f; t2[r] = 0.f; }
#pragma unroll
        for (int k = 0; k < HID; ++k) {
            float wmt = ldsMt[k * HID + lane];
            float wmb = ldsMb[k * HID + lane];
#pragma unroll
            for (int r = 0; r < R; ++r) {
                t1[r] = fmaf(lanebc(sv[r], k), wmt, t1[r]);
                t2[r] = fmaf(lanebc(hv[r], k), wmb, t2[r]);
            }
        }
        float h2[R], acc[R];
#pragma unroll
        for (int r = 0; r < R; ++r) {
            float mp = (dg[r] > 0.f) ? (t1[r] / dg[r] + t2[r] + bM0l) : 0.f;
            h2[r] = hv[r] + mp;
            acc[r] = b1l;
        }
#pragma unroll
        for (int k = 0; k < HID; ++k) {
            float w1 = ldsW1[k * HID + lane];
#pragma unroll
            for (int r = 0; r < R; ++r)
                acc[r] = fmaf(lanebc(h2[r], k), w1, acc[r]);
        }
#pragma unroll
        for (int r = 0; r < R; ++r) {
            float p = fmaxf(acc[r], 0.f) * w2l;
#pragma unroll
            for (int off = 32; off > 0; off >>= 1) p += __shfl_down(p, off);
            if (lane == 0 && (n0 + r) < N) out[n0 + r] = p + b2s;
        }
    }
}

extern "C" void kernel_launch(void* const* d_in, const int* in_sizes, int n_in,
                              void* d_out, int out_size, void* d_ws, size_t ws_size,
                              hipStream_t stream) {
    const float* x   = (const float*)d_in[0];
    const int*   ei  = (const int*)d_in[1];
    const float* W0  = (const float*)d_in[2];
    const float* b0  = (const float*)d_in[3];
    const float* W1  = (const float*)d_in[4];
    const float* b1  = (const float*)d_in[5];
    const float* W2  = (const float*)d_in[6];
    const float* b2  = (const float*)d_in[7];
    const float* M0  = (const float*)d_in[8];
    const float* bM0 = (const float*)d_in[9];

    int N = in_sizes[0] / IN_C;
    int E = in_sizes[1] / 2;
    int NB = (N + 1023) / 1024;   // <= 256 assumed (N <= 262144)

    float* h      = (float*)d_ws;                   // N*64 f32
    int*   rs     = (int*)(h + (size_t)N * HID);    // N+1
    int*   cursor = rs + (N + 1);                   // N (doubles as cnt)
    int*   bsum   = cursor + N;                     // NB
    int*   csr    = bsum + 256;                     // E
    float* out    = (float*)d_out;

    // 1) h = relu(x@W0+b0)
    k_node0<<<(N * HID + 255) / 256, 256, 0, stream>>>(x, W0, b0, h, N);
    // 2) CSR build: histogram -> scan -> scatter
    k_zero_int<<<(N + 255) / 256, 256, 0, stream>>>(cursor, N);
    k_hist<<<(E + 255) / 256, 256, 0, stream>>>(ei, cursor, E);
    k_scan1<<<NB, 256, 0, stream>>>(cursor, rs, bsum, N);
    k_scan_top<<<1, 256, 0, stream>>>(bsum, NB);
    k_scan_add<<<(N + 255) / 256, 256, 0, stream>>>(rs, cursor, bsum, N, E);
    k_scatter<<<(E + 255) / 256, 256, 0, stream>>>(ei, cursor, csr, E);
    // 3) fused gather-aggregate + message combine + layer1 + layer2
    k_final<<<1024, 512, 0, stream>>>(h, rs, csr, M0, bM0, W1, b1, W2, b2, out, N);
}

// Round 4
// 470.884 us; speedup vs baseline: 5.3667x; 1.1623x over previous
//
#include <hip/hip_runtime.h>

#define HID 64
#define IN_C 16
#define R 4

__device__ __forceinline__ float lanebcf(float v, int l) {
    return __int_as_float(__builtin_amdgcn_readlane(__float_as_int(v), l));
}
__device__ __forceinline__ int lanebci(int v, int l) {
    return __builtin_amdgcn_readlane(v, l);
}

// blocks [0,nb0): h = relu(x@W0+b0)   blocks [nb0,nb0+nbh): cnt[dst]++
__global__ void k_node0_hist(const float* __restrict__ x, const float* __restrict__ W0,
                             const float* __restrict__ b0, float* __restrict__ h, int N,
                             const int* __restrict__ ei, int* __restrict__ cnt, int E,
                             int nb0) {
    if ((int)blockIdx.x < nb0) {
        int gid = blockIdx.x * 256 + threadIdx.x;
        if (gid >= N * HID) return;
        int n = gid >> 6;
        int c = gid & 63;
        const float* xr = x + (size_t)n * IN_C;
        float acc = b0[c];
#pragma unroll
        for (int k = 0; k < IN_C; ++k) acc = fmaf(xr[k], W0[k * HID + c], acc);
        h[gid] = fmaxf(acc, 0.f);
    } else {
        int e = (blockIdx.x - nb0) * 256 + threadIdx.x;
        if (e < E) atomicAdd(&cnt[ei[E + e]], 1);
    }
}

// Per-block (1024 elems) exclusive scan of cnt -> rs; block sums -> bsum
__global__ void k_scan1(const int* __restrict__ cnt, int* __restrict__ rs,
                        int* __restrict__ bsum, int N) {
    __shared__ int lds[256];
    int t = threadIdx.x;
    int base = blockIdx.x * 1024 + t * 4;
    int v0 = 0, v1 = 0, v2 = 0, v3 = 0;
    if (base + 3 < N) {
        int4 v = *reinterpret_cast<const int4*>(cnt + base);
        v0 = v.x; v1 = v.y; v2 = v.z; v3 = v.w;
    } else {
        if (base + 0 < N) v0 = cnt[base + 0];
        if (base + 1 < N) v1 = cnt[base + 1];
        if (base + 2 < N) v2 = cnt[base + 2];
        if (base + 3 < N) v3 = cnt[base + 3];
    }
    int s = v0 + v1 + v2 + v3;
    lds[t] = s;
    __syncthreads();
#pragma unroll
    for (int off = 1; off < 256; off <<= 1) {
        int x = (t >= off) ? lds[t - off] : 0;
        __syncthreads();
        lds[t] += x;
        __syncthreads();
    }
    int excl = lds[t] - s;
    if (t == 255) bsum[blockIdx.x] = lds[255];
    if (base + 0 < N) rs[base + 0] = excl;
    if (base + 1 < N) rs[base + 1] = excl + v0;
    if (base + 2 < N) rs[base + 2] = excl + v0 + v1;
    if (base + 3 < N) rs[base + 3] = excl + v0 + v1 + v2;
}

__global__ void k_scan_top(int* __restrict__ bsum, int NB) {
    __shared__ int lds[256];
    int t = threadIdx.x;
    int v = (t < NB) ? bsum[t] : 0;
    lds[t] = v;
    __syncthreads();
#pragma unroll
    for (int off = 1; off < 256; off <<= 1) {
        int x = (t >= off) ? lds[t - off] : 0;
        __syncthreads();
        lds[t] += x;
        __syncthreads();
    }
    if (t < NB) bsum[t] = lds[t] - v;
}

__global__ void k_scan_add(int* __restrict__ rs, int* __restrict__ cursor,
                           const int* __restrict__ bsum, int N, int E) {
    int i = blockIdx.x * blockDim.x + threadIdx.x;
    if (i < N) {
        int v = rs[i] + bsum[i >> 10];
        rs[i] = v;
        cursor[i] = v;
    }
    if (i == 0) rs[N] = E;
}

__global__ void k_scatter(const int* __restrict__ ei, int* __restrict__ cursor,
                          int* __restrict__ csr, int E) {
    int e = blockIdx.x * blockDim.x + threadIdx.x;
    if (e >= E) return;
    int srcn = ei[e];
    int dstn = ei[E + e];
    int pos = atomicAdd(&cursor[dstn], 1);
    csr[pos] = srcn;
}

// Fused: gather-aggregate (lane-parallel idx, 8-deep row loads) + message MLP +
// layer1 + layer2.  Wave per R=4 nodes; weights in LDS; readlane broadcasts.
__global__ __launch_bounds__(512) void k_final(
    const float* __restrict__ h, const int* __restrict__ rs, const int* __restrict__ csr,
    const float* __restrict__ M0, const float* __restrict__ bM0,
    const float* __restrict__ W1, const float* __restrict__ b1,
    const float* __restrict__ W2, const float* __restrict__ b2,
    float* __restrict__ out, int N)
{
    __shared__ float ldsM[2 * HID * HID];   // [128][64]: rows 0-63 = Mt, 64-127 = Mb
    __shared__ float ldsW1[HID * HID];

    for (int i = threadIdx.x; i < 2 * HID * HID; i += 512) ldsM[i] = M0[i];
    for (int i = threadIdx.x; i < HID * HID; i += 512) ldsW1[i] = W1[i];
    __syncthreads();

    int lane = threadIdx.x & 63;
    int wid = (blockIdx.x * blockDim.x + threadIdx.x) >> 6;
    int nw = (gridDim.x * blockDim.x) >> 6;

    float bM0l = bM0[lane];
    float b1l  = b1[lane];
    float w2l  = W2[lane];
    float b2s  = b2[0];
    const float* hl = h + lane;

    for (int n0 = wid * R; n0 < N; n0 += nw * R) {
        float sv[R], hv[R], dg[R];
#pragma unroll
        for (int r = 0; r < R; ++r) {
            int n = n0 + r;
            bool ok = n < N;
            hv[r] = ok ? h[(size_t)n * HID + lane] : 0.f;
            int beg = ok ? rs[n] : 0;
            int end = ok ? rs[n + 1] : 0;
            dg[r] = (float)(end - beg);
            float a0 = 0.f, a1 = 0.f, a2 = 0.f, a3 = 0.f,
                  a4 = 0.f, a5 = 0.f, a6 = 0.f, a7 = 0.f;
            for (int c = beg; c < end; c += 64) {
                int cnt = end - c; if (cnt > 64) cnt = 64;
                int idxv = (lane < cnt) ? csr[c + lane] : 0;  // one coalesced 256B load
                int j = 0;
                for (; j + 8 <= cnt; j += 8) {                // 8 rows in flight
                    int i0 = lanebci(idxv, j + 0);
                    int i1 = lanebci(idxv, j + 1);
                    int i2 = lanebci(idxv, j + 2);
                    int i3 = lanebci(idxv, j + 3);
                    int i4 = lanebci(idxv, j + 4);
                    int i5 = lanebci(idxv, j + 5);
                    int i6 = lanebci(idxv, j + 6);
                    int i7 = lanebci(idxv, j + 7);
                    float v0 = hl[(size_t)i0 * HID];
                    float v1 = hl[(size_t)i1 * HID];
                    float v2 = hl[(size_t)i2 * HID];
                    float v3 = hl[(size_t)i3 * HID];
                    float v4 = hl[(size_t)i4 * HID];
                    float v5 = hl[(size_t)i5 * HID];
                    float v6 = hl[(size_t)i6 * HID];
                    float v7 = hl[(size_t)i7 * HID];
                    a0 += v0; a1 += v1; a2 += v2; a3 += v3;
                    a4 += v4; a5 += v5; a6 += v6; a7 += v7;
                }
                for (; j < cnt; ++j) a0 += hl[(size_t)lanebci(idxv, j) * HID];
            }
            sv[r] = ((a0 + a1) + (a2 + a3)) + ((a4 + a5) + (a6 + a7));
        }

        float t[R], h2[R], acc[R];
#pragma unroll
        for (int r = 0; r < R; ++r) {
            float dgc = fmaxf(dg[r], 1.f);
            sv[r] = sv[r] / dgc;         // normalized aggregate
            t[r] = bM0l;
        }
#pragma unroll
        for (int k = 0; k < HID; ++k) {
            float wmt = ldsM[k * HID + lane];
            float wmb = ldsM[(HID + k) * HID + lane];
#pragma unroll
            for (int r = 0; r < R; ++r) {
                t[r] = fmaf(lanebcf(sv[r], k), wmt, t[r]);
                t[r] = fmaf(lanebcf(hv[r], k), wmb, t[r]);
            }
        }
#pragma unroll
        for (int r = 0; r < R; ++r) {
            float mp = (dg[r] > 0.f) ? t[r] : 0.f;
            h2[r] = hv[r] + mp;
            acc[r] = b1l;
        }
#pragma unroll
        for (int k = 0; k < HID; ++k) {
            float w1 = ldsW1[k * HID + lane];
#pragma unroll
            for (int r = 0; r < R; ++r)
                acc[r] = fmaf(lanebcf(h2[r], k), w1, acc[r]);
        }
#pragma unroll
        for (int r = 0; r < R; ++r) {
            float p = fmaxf(acc[r], 0.f) * w2l;
#pragma unroll
            for (int off = 32; off > 0; off >>= 1) p += __shfl_down(p, off);
            if (lane == 0 && (n0 + r) < N) out[n0 + r] = p + b2s;
        }
    }
}

extern "C" void kernel_launch(void* const* d_in, const int* in_sizes, int n_in,
                              void* d_out, int out_size, void* d_ws, size_t ws_size,
                              hipStream_t stream) {
    const float* x   = (const float*)d_in[0];
    const int*   ei  = (const int*)d_in[1];
    const float* W0  = (const float*)d_in[2];
    const float* b0  = (const float*)d_in[3];
    const float* W1  = (const float*)d_in[4];
    const float* b1  = (const float*)d_in[5];
    const float* W2  = (const float*)d_in[6];
    const float* b2  = (const float*)d_in[7];
    const float* M0  = (const float*)d_in[8];
    const float* bM0 = (const float*)d_in[9];

    int N = in_sizes[0] / IN_C;
    int E = in_sizes[1] / 2;
    int NB = (N + 1023) / 1024;   // <= 256 assumed

    float* h      = (float*)d_ws;                   // N*64 f32
    int*   rs     = (int*)(h + (size_t)N * HID);    // N+1
    int*   cursor = rs + (N + 1);                   // N (doubles as cnt)
    int*   bsum   = cursor + N;                     // NB (<=256)
    int*   csr    = bsum + 256;                     // E
    float* out    = (float*)d_out;

    int nb0 = (N * HID + 255) / 256;
    int nbh = (E + 255) / 256;

    hipMemsetAsync(cursor, 0, (size_t)N * sizeof(int), stream);
    // 1) h = relu(x@W0+b0)  +  histogram (role-split blocks)
    k_node0_hist<<<nb0 + nbh, 256, 0, stream>>>(x, W0, b0, h, N, ei, cursor, E, nb0);
    // 2) scan -> row starts
    k_scan1<<<NB, 256, 0, stream>>>(cursor, rs, bsum, N);
    k_scan_top<<<1, 256, 0, stream>>>(bsum, NB);
    k_scan_add<<<(N + 255) / 256, 256, 0, stream>>>(rs, cursor, bsum, N, E);
    // 3) scatter edges into CSR
    k_scatter<<<(E + 255) / 256, 256, 0, stream>>>(ei, cursor, csr, E);
    // 4) fused gather-aggregate + message combine + layer1 + layer2
    k_final<<<768, 512, 0, stream>>>(h, rs, csr, M0, bM0, W1, b1, W2, b2, out, N);
}

// Round 5
// 416.855 us; speedup vs baseline: 6.0623x; 1.1296x over previous
//
#include <hip/hip_runtime.h>

#define HID 64
#define IN_C 16
#define R 4

__device__ __forceinline__ float lanebcf(float v, int l) {
    return __int_as_float(__builtin_amdgcn_readlane(__float_as_int(v), l));
}
// compile-time component select from float4
__device__ __forceinline__ float f4c(const float4& a, int c) {
    switch (c & 3) { case 0: return a.x; case 1: return a.y; case 2: return a.z; default: return a.w; }
}

// blocks [0,nb0): h = relu(x@W0+b0)   blocks [nb0,nb0+nbh): cnt[dst]++
__global__ void k_node0_hist(const float* __restrict__ x, const float* __restrict__ W0,
                             const float* __restrict__ b0, float* __restrict__ h, int N,
                             const int* __restrict__ ei, int* __restrict__ cnt, int E,
                             int nb0) {
    if ((int)blockIdx.x < nb0) {
        int gid = blockIdx.x * 256 + threadIdx.x;
        if (gid >= N * HID) return;
        int n = gid >> 6;
        int c = gid & 63;
        const float* xr = x + (size_t)n * IN_C;
        float acc = b0[c];
#pragma unroll
        for (int k = 0; k < IN_C; ++k) acc = fmaf(xr[k], W0[k * HID + c], acc);
        h[gid] = fmaxf(acc, 0.f);
    } else {
        int e = (blockIdx.x - nb0) * 256 + threadIdx.x;
        if (e < E) atomicAdd(&cnt[ei[E + e]], 1);
    }
}

// Per-block (1024 elems) exclusive scan of cnt -> rs; block sums -> bsum
__global__ void k_scan1(const int* __restrict__ cnt, int* __restrict__ rs,
                        int* __restrict__ bsum, int N) {
    __shared__ int lds[256];
    int t = threadIdx.x;
    int base = blockIdx.x * 1024 + t * 4;
    int v0 = 0, v1 = 0, v2 = 0, v3 = 0;
    if (base + 3 < N) {
        int4 v = *reinterpret_cast<const int4*>(cnt + base);
        v0 = v.x; v1 = v.y; v2 = v.z; v3 = v.w;
    } else {
        if (base + 0 < N) v0 = cnt[base + 0];
        if (base + 1 < N) v1 = cnt[base + 1];
        if (base + 2 < N) v2 = cnt[base + 2];
        if (base + 3 < N) v3 = cnt[base + 3];
    }
    int s = v0 + v1 + v2 + v3;
    lds[t] = s;
    __syncthreads();
#pragma unroll
    for (int off = 1; off < 256; off <<= 1) {
        int x = (t >= off) ? lds[t - off] : 0;
        __syncthreads();
        lds[t] += x;
        __syncthreads();
    }
    int excl = lds[t] - s;
    if (t == 255) bsum[blockIdx.x] = lds[255];
    if (base + 0 < N) rs[base + 0] = excl;
    if (base + 1 < N) rs[base + 1] = excl + v0;
    if (base + 2 < N) rs[base + 2] = excl + v0 + v1;
    if (base + 3 < N) rs[base + 3] = excl + v0 + v1 + v2;
}

// rs[i] += exclusive_scan(bsum)[i>>10]  (each block redundantly scans <=256 sums)
__global__ void k_scan_add(int* __restrict__ rs, int* __restrict__ cursor,
                           const int* __restrict__ bsum, int NB, int N, int E) {
    __shared__ int lds[256];
    int t = threadIdx.x;
    int v = (t < NB) ? bsum[t] : 0;
    lds[t] = v;
    __syncthreads();
#pragma unroll
    for (int off = 1; off < 256; off <<= 1) {
        int x = (t >= off) ? lds[t - off] : 0;
        __syncthreads();
        lds[t] += x;
        __syncthreads();
    }
    __shared__ int excl[256];
    excl[t] = lds[t] - v;
    __syncthreads();
    int i = blockIdx.x * blockDim.x + t;
    if (i < N) {
        int val = rs[i] + excl[i >> 10];
        rs[i] = val;
        cursor[i] = val;
    }
    if (i == 0) rs[N] = E;
}

__global__ void k_scatter(const int* __restrict__ ei, int* __restrict__ cursor,
                          int* __restrict__ csr, int E) {
    int e = blockIdx.x * blockDim.x + threadIdx.x;
    if (e >= E) return;
    int srcn = ei[e];
    int dstn = ei[E + e];
    int pos = atomicAdd(&cursor[dstn], 1);
    csr[pos] = srcn;
}

// Fused: group-parallel float4 gather (4 nodes simultaneously, 32 rows in flight)
// + message MLP + layer1 + layer2.  Wave per R=4 nodes; weights in LDS.
__global__ __launch_bounds__(512) void k_final(
    const float* __restrict__ h, const int* __restrict__ rs, const int* __restrict__ csr,
    const float* __restrict__ M0, const float* __restrict__ bM0,
    const float* __restrict__ W1, const float* __restrict__ b1,
    const float* __restrict__ W2, const float* __restrict__ b2,
    float* __restrict__ out, int N)
{
    __shared__ float ldsM[2 * HID * HID];   // rows 0-63 = Mt, 64-127 = Mb
    __shared__ float ldsW1[HID * HID];

    for (int i = threadIdx.x; i < 2 * HID * HID; i += 512) ldsM[i] = M0[i];
    for (int i = threadIdx.x; i < HID * HID; i += 512) ldsW1[i] = W1[i];
    __syncthreads();

    int lane = threadIdx.x & 63;
    int g    = lane >> 4;      // group 0..3 -> node n0+g
    int ql   = lane & 15;      // lane within group; covers channels 4ql..4ql+3
    int wid  = (blockIdx.x * blockDim.x + threadIdx.x) >> 6;
    int nw   = (gridDim.x * blockDim.x) >> 6;

    float bM0l = bM0[lane];
    float b1l  = b1[lane];
    float w2l  = W2[lane];
    float b2s  = b2[0];
    const float* hq = h + ql * 4;

    for (int n0 = wid * R; n0 < N; n0 += nw * R) {
        // per-lane channel-layout h rows (for residual + Mb broadcasts)
        float hv[R];
#pragma unroll
        for (int r = 0; r < R; ++r)
            hv[r] = (n0 + r < N) ? h[(size_t)(n0 + r) * HID + lane] : 0.f;

        // --- group-parallel gather: group g aggregates node n0+g ---
        int ng   = n0 + g;
        bool okg = ng < N;
        int beg  = okg ? rs[ng] : 0;
        int end  = okg ? rs[ng + 1] : 0;
        int deg  = end - beg;
        int md   = deg;
        md = max(md, __shfl_xor(md, 16));
        md = max(md, __shfl_xor(md, 32));   // wave-max degree

        float4 acc = {0.f, 0.f, 0.f, 0.f};
        for (int c = 0; c < md; c += 16) {
            int rem = deg - c;
            int idxv = (ql < rem) ? csr[beg + c + ql] : -1;
#pragma unroll
            for (int jb = 0; jb < 2; ++jb) {
                if (jb == 1 && md <= c + 8) break;
                int id[8];
#pragma unroll
                for (int u = 0; u < 8; ++u)
                    id[u] = __shfl(idxv, g * 16 + jb * 8 + u);   // group-uniform
                float4 v[8];
#pragma unroll
                for (int u = 0; u < 8; ++u) {
                    int safe = (id[u] < 0) ? 0 : id[u];
                    v[u] = *reinterpret_cast<const float4*>(hq + (size_t)safe * HID);
                }
#pragma unroll
                for (int u = 0; u < 8; ++u) {
                    if (id[u] >= 0) {
                        acc.x += v[u].x; acc.y += v[u].y;
                        acc.z += v[u].z; acc.w += v[u].w;
                    }
                }
            }
        }
        // normalize by degree (group layout)
        float rcpd = 1.f / fmaxf((float)deg, 1.f);
        acc.x *= rcpd; acc.y *= rcpd; acc.z *= rcpd; acc.w *= rcpd;
        float fdeg = (float)deg;

        // --- message MLP: t = Mt^T sv + Mb^T hv + bM0 (per-lane channel layout) ---
        float t[R], h2[R], ac[R];
#pragma unroll
        for (int r = 0; r < R; ++r) t[r] = bM0l;
#pragma unroll
        for (int k = 0; k < HID; ++k) {
            float wmt = ldsM[k * HID + lane];
            float wmb = ldsM[(HID + k) * HID + lane];
#pragma unroll
            for (int r = 0; r < R; ++r) {
                float svk = lanebcf(f4c(acc, k & 3), r * 16 + (k >> 2));
                t[r] = fmaf(svk, wmt, t[r]);
                t[r] = fmaf(lanebcf(hv[r], k), wmb, t[r]);
            }
        }
#pragma unroll
        for (int r = 0; r < R; ++r) {
            float dgr = lanebcf(fdeg, r * 16);
            float mp = (dgr > 0.f) ? t[r] : 0.f;
            h2[r] = hv[r] + mp;
            ac[r] = b1l;
        }
#pragma unroll
        for (int k = 0; k < HID; ++k) {
            float w1 = ldsW1[k * HID + lane];
#pragma unroll
            for (int r = 0; r < R; ++r)
                ac[r] = fmaf(lanebcf(h2[r], k), w1, ac[r]);
        }
#pragma unroll
        for (int r = 0; r < R; ++r) {
            float p = fmaxf(ac[r], 0.f) * w2l;
#pragma unroll
            for (int off = 32; off > 0; off >>= 1) p += __shfl_down(p, off);
            if (lane == 0 && (n0 + r) < N) out[n0 + r] = p + b2s;
        }
    }
}

extern "C" void kernel_launch(void* const* d_in, const int* in_sizes, int n_in,
                              void* d_out, int out_size, void* d_ws, size_t ws_size,
                              hipStream_t stream) {
    const float* x   = (const float*)d_in[0];
    const int*   ei  = (const int*)d_in[1];
    const float* W0  = (const float*)d_in[2];
    const float* b0  = (const float*)d_in[3];
    const float* W1  = (const float*)d_in[4];
    const float* b1  = (const float*)d_in[5];
    const float* W2  = (const float*)d_in[6];
    const float* b2  = (const float*)d_in[7];
    const float* M0  = (const float*)d_in[8];
    const float* bM0 = (const float*)d_in[9];

    int N = in_sizes[0] / IN_C;
    int E = in_sizes[1] / 2;
    int NB = (N + 1023) / 1024;   // <= 256 assumed

    float* h      = (float*)d_ws;                   // N*64 f32
    int*   rs     = (int*)(h + (size_t)N * HID);    // N+1
    int*   cursor = rs + (N + 1);                   // N (doubles as cnt)
    int*   bsum   = cursor + N;                     // 256
    int*   csr    = bsum + 256;                     // E
    float* out    = (float*)d_out;

    int nb0 = (N * HID + 255) / 256;
    int nbh = (E + 255) / 256;

    hipMemsetAsync(cursor, 0, (size_t)N * sizeof(int), stream);
    k_node0_hist<<<nb0 + nbh, 256, 0, stream>>>(x, W0, b0, h, N, ei, cursor, E, nb0);
    k_scan1<<<NB, 256, 0, stream>>>(cursor, rs, bsum, N);
    k_scan_add<<<(N + 255) / 256, 256, 0, stream>>>(rs, cursor, bsum, NB, N, E);
    k_scatter<<<(E + 255) / 256, 256, 0, stream>>>(ei, cursor, csr, E);
    k_final<<<768, 512, 0, stream>>>(h, rs, csr, M0, bM0, W1, b1, W2, b2, out, N);
}